// Round 1
// baseline (253.703 us; speedup 1.0000x reference)
//
#include <hip/hip_runtime.h>

// Lowpass IIR scan: level[t] = (1-s)*x[t] + s*level[t-1]
// B=16, T=2048, U=1024, fp32. One wave (64 lanes) per (b, 64-wide u-block),
// lane = u offset -> fully coalesced 256B per wave per timestep.
// D-deep register prefetch pipeline to keep ~32 loads in flight per wave
// (1 wave/CU occupancy needs deep ILP to cover ~900cyc HBM latency).

constexpr int B = 16;
constexpr int T = 2048;
constexpr int U = 1024;
constexpr int D = 32;   // prefetch depth (T % D == 0)

__global__ __launch_bounds__(64, 1) void lowpass_kernel(
    const float* __restrict__ in,      // [B,T,U]
    const float* __restrict__ level0,  // [1,U]
    const float* __restrict__ smooth,  // [1,U]
    float* __restrict__ out)           // [B,T,U]
{
    const int lane = threadIdx.x;      // 0..63
    const int blk  = blockIdx.x;       // 0..255
    const int b    = blk >> 4;         // blk / (U/64)
    const int ublk = blk & 15;
    const int u    = (ublk << 6) + lane;

    const float sm  = smooth[u];
    const float s   = 1.0f / (1.0f + expf(-sm));
    const float oms = 1.0f - s;
    float level     = level0[u];

    const size_t base = (size_t)b * T * U + u;
    const float* __restrict__ ip = in  + base;
    float*       __restrict__ op = out + base;

    float buf[D];
    #pragma unroll
    for (int i = 0; i < D; ++i) buf[i] = ip[(size_t)i * U];

    int t = 0;
    for (; t < T - D; t += D) {
        #pragma unroll
        for (int j = 0; j < D; ++j) {
            float x = buf[j];
            buf[j] = ip[(size_t)(t + D + j) * U];   // prefetch next tile
            level = fmaf(s, level, oms * x);        // serial chain: 1 FMA/step
            op[(size_t)(t + j) * U] = level;
        }
    }
    // epilogue: drain last tile (no more prefetch)
    #pragma unroll
    for (int j = 0; j < D; ++j) {
        float x = buf[j];
        level = fmaf(s, level, oms * x);
        op[(size_t)(t + j) * U] = level;
    }
}

extern "C" void kernel_launch(void* const* d_in, const int* in_sizes, int n_in,
                              void* d_out, int out_size, void* d_ws, size_t ws_size,
                              hipStream_t stream) {
    const float* in     = (const float*)d_in[0];  // inputs [B,T,U]
    const float* level0 = (const float*)d_in[1];  // level_var [1,U]
    const float* smooth = (const float*)d_in[2];  // smoothing_var [1,U]
    float* out          = (float*)d_out;

    dim3 grid(B * (U / 64));   // 256 blocks, 1 wave each -> ~1 wave/CU
    dim3 block(64);
    hipLaunchKernelGGL(lowpass_kernel, grid, block, 0, stream,
                       in, level0, smooth, out);
}

// Round 2
// 252.740 us; speedup vs baseline: 1.0038x; 1.0038x over previous
//
#include <hip/hip_runtime.h>

// Lowpass IIR scan: level[t] = (1-s)*x[t] + s*level[t-1], s = sigmoid(smooth).
// Chunked-scan decomposition to break the 256-wave parallelism cap:
//   chunk partial P_c = scan(chunk c, init=0) final value
//   level_in[c] = P_{c-1} + s^L * level_in[c-1]   (constant coefficient!)
// K1: compute all P_c (pure streaming read, 8 waves/CU).
// K2: recombine entry levels in-register, scan+store each chunk.

constexpr int B  = 16;
constexpr int T  = 2048;
constexpr int U  = 1024;
constexpr int C  = 8;        // chunks along T
constexpr int L  = T / C;    // 256 (power of two)
constexpr int D1 = 32;       // prefetch depth, kernel 1 (loads only)
constexpr int D2 = 16;       // prefetch depth, kernel 2 (loads + stores share vmcnt)
constexpr int BU = B * U;    // chains

__device__ __forceinline__ float sigmoidf(float x) {
    return 1.0f / (1.0f + __expf(-x));
}

// ---- Kernel 1: per-chunk partial finals P[c][chain] ----
__global__ __launch_bounds__(64, 2) void lowpass_partial(
    const float* __restrict__ in,      // [B,T,U]
    const float* __restrict__ smooth,  // [1,U]
    float* __restrict__ P)             // [C, B*U] workspace
{
    const int lane = threadIdx.x;              // 0..63
    const int blk  = blockIdx.x;               // 0 .. C*256-1
    const int c    = blk >> 8;                 // chunk
    const int r    = blk & 255;
    const int b    = r >> 4;
    const int u    = ((r & 15) << 6) + lane;

    const float s   = sigmoidf(smooth[u]);
    const float oms = 1.0f - s;

    const float* __restrict__ ip = in + (size_t)b * T * U + (size_t)(c * L) * U + u;

    float lv = 0.0f;
    float buf[D1];
    #pragma unroll
    for (int i = 0; i < D1; ++i) buf[i] = ip[(size_t)i * U];

    int t = 0;
    for (; t < L - D1; t += D1) {
        #pragma unroll
        for (int j = 0; j < D1; ++j) {
            float x = buf[j];
            buf[j] = ip[(size_t)(t + D1 + j) * U];
            lv = fmaf(s, lv, oms * x);
        }
    }
    #pragma unroll
    for (int j = 0; j < D1; ++j) {
        lv = fmaf(s, lv, oms * buf[j]);
    }

    P[(size_t)c * BU + (size_t)b * U + u] = lv;
}

// ---- Kernel 2: recombine entry level, scan chunk, store ----
__global__ __launch_bounds__(64, 2) void lowpass_scan(
    const float* __restrict__ in,      // [B,T,U]
    const float* __restrict__ level0,  // [1,U]
    const float* __restrict__ smooth,  // [1,U]
    const float* __restrict__ P,       // [C, B*U]
    float* __restrict__ out)           // [B,T,U]
{
    const int lane = threadIdx.x;
    const int blk  = blockIdx.x;
    const int c    = blk >> 8;
    const int r    = blk & 255;
    const int b    = r >> 4;
    const int u    = ((r & 15) << 6) + lane;
    const int chain = b * U + u;

    const float s   = sigmoidf(smooth[u]);
    const float oms = 1.0f - s;

    // s^L via repeated squaring (L = 256 = 2^8)
    float sL = s;
    #pragma unroll
    for (int i = 0; i < 8; ++i) sL *= sL;

    // entry level for this chunk
    float lv = level0[u];
    for (int i = 0; i < c; ++i) {
        lv = fmaf(sL, lv, P[(size_t)i * BU + chain]);
    }

    const size_t base = (size_t)b * T * U + (size_t)(c * L) * U + u;
    const float* __restrict__ ip = in  + base;
    float*       __restrict__ op = out + base;

    float buf[D2];
    #pragma unroll
    for (int i = 0; i < D2; ++i) buf[i] = ip[(size_t)i * U];

    int t = 0;
    for (; t < L - D2; t += D2) {
        #pragma unroll
        for (int j = 0; j < D2; ++j) {
            float x = buf[j];
            buf[j] = ip[(size_t)(t + D2 + j) * U];
            lv = fmaf(s, lv, oms * x);
            op[(size_t)(t + j) * U] = lv;
        }
    }
    #pragma unroll
    for (int j = 0; j < D2; ++j) {
        lv = fmaf(s, lv, oms * buf[j]);
        op[(size_t)(t + j) * U] = lv;
    }
}

extern "C" void kernel_launch(void* const* d_in, const int* in_sizes, int n_in,
                              void* d_out, int out_size, void* d_ws, size_t ws_size,
                              hipStream_t stream) {
    const float* in     = (const float*)d_in[0];  // inputs [B,T,U]
    const float* level0 = (const float*)d_in[1];  // level_var [1,U]
    const float* smooth = (const float*)d_in[2];  // smoothing_var [1,U]
    float* out          = (float*)d_out;
    float* P            = (float*)d_ws;           // C*B*U floats = 512 KB

    dim3 block(64);
    dim3 grid(C * (BU / 64));   // 8 * 256 = 2048 blocks

    hipLaunchKernelGGL(lowpass_partial, grid, block, 0, stream, in, smooth, P);
    hipLaunchKernelGGL(lowpass_scan,    grid, block, 0, stream, in, level0, smooth, P, out);
}